// Round 10
// baseline (603.880 us; speedup 1.0000x reference)
//
#include <hip/hip_runtime.h>

static constexpr int N = 100000;
static constexpr int E = 1600000;
static constexpr int F = 128;     // IN_F == HID_F
static constexpr int NB = (N + 127) / 128;              // 782 dst buckets of 128 nodes
static constexpr int PCHUNK = 16384;                     // edges per partition block
static constexpr int PGRID = (E + PCHUNK - 1) / PCHUNK;  // 98
static constexpr int CAPB = 2560;                        // fixed bucket stride (mean 2046, +11 sigma)
static const size_t SL_N = (size_t)N * 16;               // ushorts per 16-col slice (3.2 MB < 4MB L2/XCD)

typedef __attribute__((ext_vector_type(8))) short bf16x8;
typedef __attribute__((ext_vector_type(4))) float f32x4;

__device__ inline unsigned short f2bf(float f) {  // round-to-nearest-even bf16
    unsigned int u = __builtin_bit_cast(unsigned int, f);
    unsigned int r = u + 0x7FFF + ((u >> 16) & 1);
    return (unsigned short)(r >> 16);
}
__device__ inline float bf_lo(unsigned int v) {
    return __builtin_bit_cast(float, v << 16);
}
__device__ inline float bf_hi(unsigned int v) {
    return __builtin_bit_cast(float, v & 0xffff0000u);
}

// ---------------- merged prep: conv_feat -> sliced hS (6250 blocks) | prep_w (320 blocks) ----------------
__global__ __launch_bounds__(256) void prep_all_k(const float* __restrict__ feat,
                                                  unsigned short* __restrict__ hS,
                                                  const float* __restrict__ Ws0,
                                                  const float* __restrict__ Wn0,
                                                  const float* __restrict__ Ws1,
                                                  const float* __restrict__ Wn1,
                                                  const float* __restrict__ Ws2,
                                                  const float* __restrict__ Wn2,
                                                  unsigned short* __restrict__ Wt0,
                                                  unsigned short* __restrict__ Wt1,
                                                  unsigned short* __restrict__ Wc2) {
    const int t = threadIdx.x;
    const int bid = blockIdx.x;
    if (bid < 6250) {
        const int nloc = t & 15;
        const int sh = t >> 4;            // col octet 0..15
        const int node = bid * 16 + nloc;
        float4 a = *(const float4*)&feat[(size_t)node * F + sh * 8];
        float4 b = *(const float4*)&feat[(size_t)node * F + sh * 8 + 4];
        unsigned long long p0 = (unsigned long long)f2bf(a.x)
                              | ((unsigned long long)f2bf(a.y) << 16)
                              | ((unsigned long long)f2bf(a.z) << 32)
                              | ((unsigned long long)f2bf(a.w) << 48);
        unsigned long long p1 = (unsigned long long)f2bf(b.x)
                              | ((unsigned long long)f2bf(b.y) << 16)
                              | ((unsigned long long)f2bf(b.z) << 32)
                              | ((unsigned long long)f2bf(b.w) << 48);
        unsigned long long* dstp =
            (unsigned long long*)&hS[(size_t)(sh >> 1) * SL_N + (size_t)node * 16 + (sh & 1) * 8];
        dstp[0] = p0; dstp[1] = p1;
    } else {
        int idx = (bid - 6250) * 256 + t;
        if (idx < 32768) {
            int n = idx >> 8, k = idx & 255;
            float v = (k < 128) ? Ws0[k * 128 + n] : Wn0[(k - 128) * 128 + n];
            Wt0[n * 256 + k] = f2bf(v);
        } else if (idx < 65536) {
            int j = idx - 32768;
            int n = j >> 8, k = j & 255;
            float v = (k < 128) ? Ws1[k * 128 + n] : Wn1[(k - 128) * 128 + n];
            Wt1[n * 256 + k] = f2bf(v);
        } else if (idx < 65536 + 16384) {
            int j = idx - 65536;
            int c = j >> 7, k = j & 127;
            float v = (c < 64) ? Ws2[k * 64 + c] : Wn2[k * 64 + (c - 64)];
            Wc2[c * 128 + k] = f2bf(v);
        }
    }
}

// ---------------- partition edges into fixed-stride buckets (run-clustered writes) ----------------
__global__ __launch_bounds__(256) void partition_k(const int* __restrict__ src,
                                                   const int* __restrict__ dst,
                                                   int* __restrict__ bcur,
                                                   unsigned int* __restrict__ ebuf) {
    __shared__ int sh_hist[NB];
    __shared__ int sh_base[NB];
    __shared__ int sh_cur[NB];
    const int t = threadIdx.x;
    for (int i = t; i < NB; i += 256) sh_hist[i] = 0;
    __syncthreads();
    const int cb = blockIdx.x * PCHUNK;
    #pragma unroll
    for (int j = 0; j < PCHUNK / 1024; ++j) {
        int idx = cb + j * 1024 + t * 4;
        if (idx < E) {
            int4 d4 = *(const int4*)&dst[idx];
            atomicAdd(&sh_hist[d4.x >> 7], 1);
            atomicAdd(&sh_hist[d4.y >> 7], 1);
            atomicAdd(&sh_hist[d4.z >> 7], 1);
            atomicAdd(&sh_hist[d4.w >> 7], 1);
        }
    }
    __syncthreads();
    for (int i = t; i < NB; i += 256) {
        int c = sh_hist[i];
        sh_base[i] = c ? (i * CAPB + atomicAdd(&bcur[i], c)) : 0;
        sh_cur[i] = 0;
    }
    __syncthreads();
    #pragma unroll
    for (int j = 0; j < PCHUNK / 1024; ++j) {
        int idx = cb + j * 1024 + t * 4;
        if (idx < E) {
            int4 s4 = *(const int4*)&src[idx];
            int4 d4 = *(const int4*)&dst[idx];
            {
                int b = d4.x >> 7; int p = atomicAdd(&sh_cur[b], 1);
                ebuf[sh_base[b] + p] = (unsigned)s4.x | ((unsigned)(d4.x & 127) << 17);
            }
            {
                int b = d4.y >> 7; int p = atomicAdd(&sh_cur[b], 1);
                ebuf[sh_base[b] + p] = (unsigned)s4.y | ((unsigned)(d4.y & 127) << 17);
            }
            {
                int b = d4.z >> 7; int p = atomicAdd(&sh_cur[b], 1);
                ebuf[sh_base[b] + p] = (unsigned)s4.z | ((unsigned)(d4.z & 127) << 17);
            }
            {
                int b = d4.w >> 7; int p = atomicAdd(&sh_cur[b], 1);
                ebuf[sh_base[b] + p] = (unsigned)s4.w | ((unsigned)(d4.w & 127) << 17);
            }
        }
    }
}

// ---------------- per-bucket LDS counting sort -> esrc (padded), row_beg, degs, inv_deg ----------------
__global__ __launch_bounds__(256) void csr_sort_k(const unsigned int* __restrict__ ebuf,
                                                  const int* __restrict__ bcur,
                                                  int* __restrict__ row_beg,
                                                  int* __restrict__ degs,
                                                  float* __restrict__ inv_deg,
                                                  int* __restrict__ esrc) {
    __shared__ unsigned int sh_e[CAPB];
    __shared__ int sh_o[CAPB];
    __shared__ int sh_hist[128];
    __shared__ int sh_excl[128];
    __shared__ int sh_cur[128];
    __shared__ int sh_w0;
    const int b = blockIdx.x, t = threadIdx.x;
    const int e0 = b * CAPB;
    const int ec = bcur[b];
    if (t < 128) { sh_hist[t] = 0; sh_cur[t] = 0; }
    __syncthreads();
    for (int i = t; i < ec; i += 256) {
        unsigned int e = ebuf[e0 + i];
        sh_e[i] = e;
        atomicAdd(&sh_hist[e >> 17], 1);
    }
    __syncthreads();
    int v = 0;
    if (t < 128) v = sh_hist[t];
    int incl = v;
    const int lane = t & 63;
    #pragma unroll
    for (int off = 1; off < 64; off <<= 1) {
        int u = __shfl_up(incl, off);
        if (lane >= off) incl += u;
    }
    if (t == 63) sh_w0 = incl;
    __syncthreads();
    if (t >= 64 && t < 128) incl += sh_w0;
    if (t < 128) {
        sh_excl[t] = incl - v;
        int node = b * 128 + t;
        if (node < N) {
            row_beg[node] = e0 + incl - v;
            degs[node] = v;
            inv_deg[node] = 1.0f / fmaxf((float)v, 1.0f);
        }
    }
    __syncthreads();
    for (int i = t; i < ec; i += 256) {
        unsigned int e = sh_e[i];
        int l = e >> 17;
        int pos = sh_excl[l] + atomicAdd(&sh_cur[l], 1);
        sh_o[pos] = (int)(e & 0x1FFFF);
    }
    __syncthreads();
    for (int i = t; i < ec; i += 256) esrc[e0 + i] = sh_o[i];
}

// ---------------- sliced mean aggregation v2: XCD-resident table + 128 lines in flight ----------------
// slice = bid & (NSL-1)  (-> XCD steering, residency proven by R6's FETCH=59MB);
// wave = 4 nodes x (16 edge-slots x 4 col-lanes), j-unroll 2 -> 8 outstanding vmem x 16 lines.
// Reduction over slots hoisted OUT of the j-loop (one shfl tree per node).
// OUTMODE 0: bf16 into outS slice; OUTMODE 1: f32 add into out64[node][64].
template <int NSL, int OUTMODE>
__global__ __launch_bounds__(256) void agg_slice_k(const unsigned short* __restrict__ tabS,
                                                   unsigned short* __restrict__ outS,
                                                   float* __restrict__ out64,
                                                   const int* __restrict__ row_beg,
                                                   const int* __restrict__ degs,
                                                   const int* __restrict__ esrc,
                                                   const float* __restrict__ inv_deg) {
    const int slice = blockIdx.x & (NSL - 1);
    const int group = blockIdx.x / NSL;
    const int lane = threadIdx.x & 63;
    const int wv = threadIdx.x >> 6;
    const int slot = lane >> 2;     // edge slot 0..15
    const int c = lane & 3;         // col quad: cols c*4..c*4+3 of the 16-col slice
    const unsigned short* tab = tabS + (size_t)slice * SL_N;
    const int n0 = group * 16 + wv * 4;   // grid/NSL = N/16 exactly
    int beg[4], cnt[4];
    #pragma unroll
    for (int u = 0; u < 4; ++u) {
        beg[u] = row_beg[n0 + u];
        cnt[u] = degs[n0 + u];
    }
    const int wmax = max(max(cnt[0], cnt[1]), max(cnt[2], cnt[3]));
    float a[4][4];
    #pragma unroll
    for (int u = 0; u < 4; ++u) {
        a[u][0] = 0.f; a[u][1] = 0.f; a[u][2] = 0.f; a[u][3] = 0.f;
    }
    for (int j = 0; j < wmax; j += 32) {
        uint2 v[4][2];
        #pragma unroll
        for (int u = 0; u < 4; ++u) {
            #pragma unroll
            for (int h = 0; h < 2; ++h) {
                int e = j + h * 16 + slot;
                if (e < cnt[u]) {
                    int s = __builtin_nontemporal_load(&esrc[beg[u] + e]);
                    v[u][h] = *(const uint2*)&tab[(size_t)s * 16 + c * 4];
                } else {
                    v[u][h].x = 0u; v[u][h].y = 0u;
                }
            }
        }
        #pragma unroll
        for (int u = 0; u < 4; ++u) {
            #pragma unroll
            for (int h = 0; h < 2; ++h) {
                a[u][0] += bf_lo(v[u][h].x); a[u][1] += bf_hi(v[u][h].x);
                a[u][2] += bf_lo(v[u][h].y); a[u][3] += bf_hi(v[u][h].y);
            }
        }
    }
    // reduce partial sums over the 16 slots (lane bits 2..5)
    #pragma unroll
    for (int st = 4; st <= 32; st <<= 1) {
        #pragma unroll
        for (int u = 0; u < 4; ++u) {
            a[u][0] += __shfl_xor(a[u][0], st);
            a[u][1] += __shfl_xor(a[u][1], st);
            a[u][2] += __shfl_xor(a[u][2], st);
            a[u][3] += __shfl_xor(a[u][3], st);
        }
    }
    if (slot == 0) {
        #pragma unroll
        for (int u = 0; u < 4; ++u) {
            const float s = inv_deg[n0 + u];
            if (OUTMODE == 0) {
                uint2 o;
                o.x = (unsigned int)f2bf(a[u][0] * s) | ((unsigned int)f2bf(a[u][1] * s) << 16);
                o.y = (unsigned int)f2bf(a[u][2] * s) | ((unsigned int)f2bf(a[u][3] * s) << 16);
                *(uint2*)&outS[(size_t)slice * SL_N + (size_t)(n0 + u) * 16 + c * 4] = o;
            } else {
                float4* p = (float4*)&out64[(size_t)(n0 + u) * 64 + slice * 16 + c * 4];
                float4 pv = *p;
                pv.x += a[u][0] * s; pv.y += a[u][1] * s;
                pv.z += a[u][2] * s; pv.w += a[u][3] * s;
                *p = pv;
            }
        }
    }
}

// ---------------- layers 0/1 fused linear via MFMA (sliced A, sliced out) ----------------
__global__ __launch_bounds__(256) void linear01_k(const unsigned short* __restrict__ hS,
                                                  const unsigned short* __restrict__ aggS,
                                                  const unsigned short* __restrict__ Wt,
                                                  const float* __restrict__ bias,
                                                  unsigned short* __restrict__ outS) {
    constexpr int CPW = 32;
    constexpr int NT = 2;
    const int lane = threadIdx.x & 63;
    const int wv = threadIdx.x >> 6;
    const int col0 = wv * CPW;
    const int lc = lane & 15;
    const int lg = lane >> 4;
    bf16x8 bfrag[NT][8];
    float bias_c[NT];
    #pragma unroll
    for (int nt = 0; nt < NT; ++nt) {
        int col = col0 + nt * 16 + lc;
        bias_c[nt] = bias[col];
        #pragma unroll
        for (int ks = 0; ks < 8; ++ks)
            bfrag[nt][ks] = *(const bf16x8*)&Wt[col * 256 + ks * 32 + lg * 8];
    }
    const int sl_sub = lg >> 1;
    const int el_off = (lg & 1) * 8;
    const int i0base = blockIdx.x * 128;
    for (int s = 0; s < 8; ++s) {
        int i0 = i0base + s * 16;
        if (i0 >= N) return;
        const int arow = i0 + lc;
        f32x4 acc[NT];
        #pragma unroll
        for (int nt = 0; nt < NT; ++nt) {
            acc[nt][0] = bias_c[nt]; acc[nt][1] = bias_c[nt];
            acc[nt][2] = bias_c[nt]; acc[nt][3] = bias_c[nt];
        }
        #pragma unroll
        for (int ks = 0; ks < 8; ++ks) {
            const unsigned short* base = (ks < 4) ? hS : aggS;
            int sl = (ks & 3) * 2 + sl_sub;
            bf16x8 af = *(const bf16x8*)&base[(size_t)sl * SL_N + (size_t)arow * 16 + el_off];
            #pragma unroll
            for (int nt = 0; nt < NT; ++nt)
                acc[nt] = __builtin_amdgcn_mfma_f32_16x16x32_bf16(af, bfrag[nt][ks], acc[nt], 0, 0, 0);
        }
        #pragma unroll
        for (int nt = 0; nt < NT; ++nt) {
            #pragma unroll
            for (int r = 0; r < 4; ++r) {
                int orow = i0 + lg * 4 + r;
                float v = fmaxf(acc[nt][r], 0.f);
                int so = (col0 + nt * 16) >> 4;  // wave-uniform output slice
                outS[(size_t)so * SL_N + (size_t)orow * 16 + lc] = f2bf(v);
            }
        }
    }
}

// ---------------- layer2: P = h@Ws2 + b2 -> f32 out; Q = h@Wn2 -> sliced bf16 Qs[4][N][16] ----------------
__global__ __launch_bounds__(256) void linear2_k(const unsigned short* __restrict__ hS,
                                                 const unsigned short* __restrict__ Wc,
                                                 const float* __restrict__ bias,
                                                 float* __restrict__ out,
                                                 unsigned short* __restrict__ Qs) {
    constexpr int CPW = 32;
    constexpr int NT = 2;
    const int lane = threadIdx.x & 63;
    const int wv = threadIdx.x >> 6;
    const int col0 = wv * CPW;   // wv 0/1: P cols, wv 2/3: Q cols (col-64)
    const int lc = lane & 15;
    const int lg = lane >> 4;
    bf16x8 bfrag[NT][4];
    float bias_c[NT];
    #pragma unroll
    for (int nt = 0; nt < NT; ++nt) {
        int col = col0 + nt * 16 + lc;
        bias_c[nt] = (wv < 2) ? bias[col] : 0.f;
        #pragma unroll
        for (int ks = 0; ks < 4; ++ks)
            bfrag[nt][ks] = *(const bf16x8*)&Wc[col * 128 + ks * 32 + lg * 8];
    }
    const int sl_sub = lg >> 1;
    const int el_off = (lg & 1) * 8;
    const int i0base = blockIdx.x * 128;
    for (int s = 0; s < 8; ++s) {
        int i0 = i0base + s * 16;
        if (i0 >= N) return;
        const int arow = i0 + lc;
        f32x4 acc[NT];
        #pragma unroll
        for (int nt = 0; nt < NT; ++nt) {
            acc[nt][0] = bias_c[nt]; acc[nt][1] = bias_c[nt];
            acc[nt][2] = bias_c[nt]; acc[nt][3] = bias_c[nt];
        }
        #pragma unroll
        for (int ks = 0; ks < 4; ++ks) {
            int sl = ks * 2 + sl_sub;
            bf16x8 af = *(const bf16x8*)&hS[(size_t)sl * SL_N + (size_t)arow * 16 + el_off];
            #pragma unroll
            for (int nt = 0; nt < NT; ++nt)
                acc[nt] = __builtin_amdgcn_mfma_f32_16x16x32_bf16(af, bfrag[nt][ks], acc[nt], 0, 0, 0);
        }
        #pragma unroll
        for (int nt = 0; nt < NT; ++nt) {
            int col = col0 + nt * 16 + lc;
            #pragma unroll
            for (int r = 0; r < 4; ++r) {
                int orow = i0 + lg * 4 + r;
                float v = acc[nt][r];
                if (wv < 2) {
                    out[(size_t)orow * 64 + col] = v;
                } else {
                    int q = col - 64;                 // 0..63
                    int sq = (wv - 2) * 2 + nt;       // wave-uniform slice 0..3
                    Qs[(size_t)sq * SL_N + (size_t)orow * 16 + (q & 15)] = f2bf(v);
                }
            }
        }
    }
}

extern "C" void kernel_launch(void* const* d_in, const int* in_sizes, int n_in,
                              void* d_out, int out_size, void* d_ws, size_t ws_size,
                              hipStream_t stream) {
    const float* feat = (const float*)d_in[0];
    const int*   src  = (const int*)d_in[1];
    const int*   dst  = (const int*)d_in[2];
    const float* Ws0  = (const float*)d_in[3];
    const float* Wn0  = (const float*)d_in[4];
    const float* b0   = (const float*)d_in[5];
    const float* Ws1  = (const float*)d_in[6];
    const float* Wn1  = (const float*)d_in[7];
    const float* b1   = (const float*)d_in[8];
    const float* Ws2  = (const float*)d_in[9];
    const float* Wn2  = (const float*)d_in[10];
    const float* b2   = (const float*)d_in[11];
    float* out = (float*)d_out;

    char* ws = (char*)d_ws;
    size_t off = 0;
    auto alloc = [&](size_t bytes) {
        void* p = ws + off;
        off = (off + bytes + 255) & ~(size_t)255;
        return p;
    };
    unsigned short* hSA  = (unsigned short*)alloc(SL_N * 8 * 2);
    unsigned short* hSB  = (unsigned short*)alloc(SL_N * 8 * 2);
    unsigned short* aggS = (unsigned short*)alloc(SL_N * 8 * 2);
    unsigned short* Qs   = (unsigned short*)alloc(SL_N * 4 * 2);
    unsigned short* Wt0  = (unsigned short*)alloc((size_t)128 * 256 * 2);
    unsigned short* Wt1  = (unsigned short*)alloc((size_t)128 * 256 * 2);
    unsigned short* Wc2  = (unsigned short*)alloc((size_t)128 * 128 * 2);
    float* inv     = (float*)alloc((size_t)N * 4);
    int*   row_beg = (int*)alloc((size_t)N * 4);
    int*   degs    = (int*)alloc((size_t)N * 4);
    int*   bcur    = (int*)alloc((size_t)NB * 4);
    unsigned int* ebuf = (unsigned int*)alloc((size_t)NB * CAPB * 4);
    int*   esrc    = (int*)alloc((size_t)NB * CAPB * 4);
    (void)ws_size; (void)in_sizes; (void)n_in; (void)out_size;

    // ---- prep (conv + weights) and CSR build ----
    hipMemsetAsync(bcur, 0, (size_t)NB * 4, stream);
    prep_all_k<<<6250 + 320, 256, 0, stream>>>(
        feat, hSA, Ws0, Wn0, Ws1, Wn1, Ws2, Wn2, Wt0, Wt1, Wc2);
    partition_k<<<PGRID, 256, 0, stream>>>(src, dst, bcur, ebuf);
    csr_sort_k<<<NB, 256, 0, stream>>>(ebuf, bcur, row_beg, degs, inv, esrc);

    const int lin_grid = (N + 127) / 128;
    const int agg_grid8 = 8 * (N / 16);   // 50000 blocks; slice = bid & 7 -> XCD
    const int agg_grid4 = 4 * (N / 16);   // 25000 blocks; slice = bid & 3
    // layer 0
    agg_slice_k<8, 0><<<agg_grid8, 256, 0, stream>>>(hSA, aggS, nullptr, row_beg, degs, esrc, inv);
    linear01_k<<<lin_grid, 256, 0, stream>>>(hSA, aggS, Wt0, b0, hSB);
    // layer 1
    agg_slice_k<8, 0><<<agg_grid8, 256, 0, stream>>>(hSB, aggS, nullptr, row_beg, degs, esrc, inv);
    linear01_k<<<lin_grid, 256, 0, stream>>>(hSB, aggS, Wt1, b1, hSA);
    // layer 2: P -> out (f32), Q -> Qs; then out += mean-gather(Q)
    linear2_k<<<lin_grid, 256, 0, stream>>>(hSA, Wc2, b2, out, Qs);
    agg_slice_k<4, 1><<<agg_grid4, 256, 0, stream>>>(Qs, nullptr, out, row_beg, degs, esrc, inv);
}

// Round 11
// 305.740 us; speedup vs baseline: 1.9751x; 1.9751x over previous
//
#include <hip/hip_runtime.h>

static constexpr int N = 100000;
static constexpr int E = 1600000;
static constexpr int F = 128;     // IN_F == HID_F
static constexpr int NB = (N + 127) / 128;              // 782 dst buckets of 128 nodes
static constexpr int PCHUNK = 16384;                     // edges per partition block
static constexpr int PGRID = (E + PCHUNK - 1) / PCHUNK;  // 98
static constexpr int CAPB = 2560;                        // fixed bucket stride (mean 2046, +11 sigma)
static constexpr int NPAD = NB * 128;                    // 100096 padded rows

typedef __attribute__((ext_vector_type(8))) short bf16x8;
typedef __attribute__((ext_vector_type(4))) float f32x4;

__device__ inline unsigned short f2bf(float f) {  // round-to-nearest-even bf16
    unsigned int u = __builtin_bit_cast(unsigned int, f);
    unsigned int r = u + 0x7FFF + ((u >> 16) & 1);
    return (unsigned short)(r >> 16);
}
__device__ inline float bf_lo(unsigned int v) {
    return __builtin_bit_cast(float, v << 16);
}
__device__ inline float bf_hi(unsigned int v) {
    return __builtin_bit_cast(float, v & 0xffff0000u);
}

// ---------------- merged prep: conv_feat (12500) | prep_w (320) | zero bcur (1) ----------------
__global__ __launch_bounds__(256) void prep_all_k(const float* __restrict__ feat,
                                                  unsigned short* __restrict__ hA,
                                                  const float* __restrict__ Ws0,
                                                  const float* __restrict__ Wn0,
                                                  const float* __restrict__ Ws1,
                                                  const float* __restrict__ Wn1,
                                                  const float* __restrict__ Ws2,
                                                  const float* __restrict__ Wn2,
                                                  unsigned short* __restrict__ Wt0,
                                                  unsigned short* __restrict__ Wt1,
                                                  unsigned short* __restrict__ Wc2,
                                                  int* __restrict__ bcur) {
    const int t = threadIdx.x;
    const int bid = blockIdx.x;
    if (bid < 12500) {
        int idx = bid * 256 + t;   // 8 nodes/block, 32 threads per node row
        int node = idx >> 5;
        int c4 = idx & 31;
        if (node < N) {
            float4 v = *(const float4*)&feat[(size_t)node * F + c4 * 4];
            unsigned long long p = (unsigned long long)f2bf(v.x)
                                 | ((unsigned long long)f2bf(v.y) << 16)
                                 | ((unsigned long long)f2bf(v.z) << 32)
                                 | ((unsigned long long)f2bf(v.w) << 48);
            *(unsigned long long*)&hA[(size_t)node * F + c4 * 4] = p;
        }
    } else if (bid < 12500 + 320) {
        int idx = (bid - 12500) * 256 + t;
        if (idx < 32768) {
            int n = idx >> 8, k = idx & 255;
            float v = (k < 128) ? Ws0[k * 128 + n] : Wn0[(k - 128) * 128 + n];
            Wt0[n * 256 + k] = f2bf(v);
        } else if (idx < 65536) {
            int j = idx - 32768;
            int n = j >> 8, k = j & 255;
            float v = (k < 128) ? Ws1[k * 128 + n] : Wn1[(k - 128) * 128 + n];
            Wt1[n * 256 + k] = f2bf(v);
        } else if (idx < 65536 + 16384) {
            int j = idx - 65536;
            int c = j >> 7, k = j & 127;
            float v = (c < 64) ? Ws2[k * 64 + c] : Wn2[k * 64 + (c - 64)];
            Wc2[c * 128 + k] = f2bf(v);
        }
    } else {
        // zero bucket cursors (replaces hipMemsetAsync dispatch)
        for (int i = t; i < NB; i += 256) bcur[i] = 0;
    }
}

// ---------------- partition edges into fixed-stride buckets (run-clustered writes) ----------------
__global__ __launch_bounds__(256) void partition_k(const int* __restrict__ src,
                                                   const int* __restrict__ dst,
                                                   int* __restrict__ bcur,
                                                   unsigned int* __restrict__ ebuf) {
    __shared__ int sh_hist[NB];
    __shared__ int sh_base[NB];
    __shared__ int sh_cur[NB];
    const int t = threadIdx.x;
    for (int i = t; i < NB; i += 256) sh_hist[i] = 0;
    __syncthreads();
    const int cb = blockIdx.x * PCHUNK;
    #pragma unroll
    for (int j = 0; j < PCHUNK / 1024; ++j) {
        int idx = cb + j * 1024 + t * 4;
        if (idx < E) {
            int4 d4 = *(const int4*)&dst[idx];
            atomicAdd(&sh_hist[d4.x >> 7], 1);
            atomicAdd(&sh_hist[d4.y >> 7], 1);
            atomicAdd(&sh_hist[d4.z >> 7], 1);
            atomicAdd(&sh_hist[d4.w >> 7], 1);
        }
    }
    __syncthreads();
    for (int i = t; i < NB; i += 256) {
        int c = sh_hist[i];
        sh_base[i] = c ? (i * CAPB + atomicAdd(&bcur[i], c)) : 0;
        sh_cur[i] = 0;
    }
    __syncthreads();
    #pragma unroll
    for (int j = 0; j < PCHUNK / 1024; ++j) {
        int idx = cb + j * 1024 + t * 4;
        if (idx < E) {
            int4 s4 = *(const int4*)&src[idx];
            int4 d4 = *(const int4*)&dst[idx];
            {
                int b = d4.x >> 7; int p = atomicAdd(&sh_cur[b], 1);
                ebuf[sh_base[b] + p] = (unsigned)s4.x | ((unsigned)(d4.x & 127) << 17);
            }
            {
                int b = d4.y >> 7; int p = atomicAdd(&sh_cur[b], 1);
                ebuf[sh_base[b] + p] = (unsigned)s4.y | ((unsigned)(d4.y & 127) << 17);
            }
            {
                int b = d4.z >> 7; int p = atomicAdd(&sh_cur[b], 1);
                ebuf[sh_base[b] + p] = (unsigned)s4.z | ((unsigned)(d4.z & 127) << 17);
            }
            {
                int b = d4.w >> 7; int p = atomicAdd(&sh_cur[b], 1);
                ebuf[sh_base[b] + p] = (unsigned)s4.w | ((unsigned)(d4.w & 127) << 17);
            }
        }
    }
}

// ---------------- per-bucket LDS counting sort -> esrc (padded), row_beg, degs, inv_deg ----------------
__global__ __launch_bounds__(256) void csr_sort_k(const unsigned int* __restrict__ ebuf,
                                                  const int* __restrict__ bcur,
                                                  int* __restrict__ row_beg,
                                                  int* __restrict__ degs,
                                                  float* __restrict__ inv_deg,
                                                  int* __restrict__ esrc) {
    __shared__ unsigned int sh_e[CAPB];
    __shared__ int sh_o[CAPB];
    __shared__ int sh_hist[128];
    __shared__ int sh_excl[128];
    __shared__ int sh_cur[128];
    __shared__ int sh_w0;
    const int b = blockIdx.x, t = threadIdx.x;
    const int e0 = b * CAPB;
    const int ec = bcur[b];
    if (t < 128) { sh_hist[t] = 0; sh_cur[t] = 0; }
    __syncthreads();
    for (int i = t; i < ec; i += 256) {
        unsigned int e = ebuf[e0 + i];
        sh_e[i] = e;
        atomicAdd(&sh_hist[e >> 17], 1);
    }
    __syncthreads();
    int v = 0;
    if (t < 128) v = sh_hist[t];
    int incl = v;
    const int lane = t & 63;
    #pragma unroll
    for (int off = 1; off < 64; off <<= 1) {
        int u = __shfl_up(incl, off);
        if (lane >= off) incl += u;
    }
    if (t == 63) sh_w0 = incl;
    __syncthreads();
    if (t >= 64 && t < 128) incl += sh_w0;
    if (t < 128) {
        sh_excl[t] = incl - v;
        int node = b * 128 + t;
        if (node < N) {
            row_beg[node] = e0 + incl - v;
            degs[node] = v;
            inv_deg[node] = 1.0f / fmaxf((float)v, 1.0f);
        }
    }
    __syncthreads();
    for (int i = t; i < ec; i += 256) {
        unsigned int e = sh_e[i];
        int l = e >> 17;
        int pos = sh_excl[l] + atomicAdd(&sh_cur[l], 1);
        sh_o[pos] = (int)(e & 0x1FFFF);
    }
    __syncthreads();
    for (int i = t; i < ec; i += 256) esrc[e0 + i] = sh_o[i];
}

// ---------------- 128-col mean aggregation: 4 nodes/wave, 16B loads, unroll 8 ----------------
// Proven ceiling form: 32 random 256B rows in flight per wave, ~3.6 TB/s delivery.
__global__ __launch_bounds__(256) void aggregate128_k(const unsigned short* __restrict__ h,
                                                      unsigned short* __restrict__ agg_out,
                                                      const int* __restrict__ row_beg,
                                                      const int* __restrict__ degs,
                                                      const int* __restrict__ esrc,
                                                      const float* __restrict__ inv_deg) {
    const int lane = threadIdx.x & 63;
    const int wv = threadIdx.x >> 6;
    const int slot = lane >> 4;
    const int cl = lane & 15;
    const int node = blockIdx.x * 16 + wv * 4 + slot;  // grid = N/16 exactly
    const int beg = row_beg[node];
    const int cnt = degs[node];
    const float sinv = inv_deg[node];
    int wmax = cnt;
    wmax = max(wmax, __shfl_xor(wmax, 16));
    wmax = max(wmax, __shfl_xor(wmax, 32));
    float a0 = 0.f, a1 = 0.f, a2 = 0.f, a3 = 0.f;
    float a4 = 0.f, a5 = 0.f, a6 = 0.f, a7 = 0.f;
    for (int j = 0; j < wmax; j += 8) {
        int idx[8];
        uint4 v[8];
        #pragma unroll
        for (int u = 0; u < 8; ++u)
            idx[u] = (j + u < cnt) ? __builtin_nontemporal_load(&esrc[beg + j + u]) : -1;
        #pragma unroll
        for (int u = 0; u < 8; ++u) {
            if (idx[u] >= 0)
                v[u] = *(const uint4*)&h[(size_t)idx[u] * F + cl * 8];
            else { v[u].x = 0u; v[u].y = 0u; v[u].z = 0u; v[u].w = 0u; }
        }
        #pragma unroll
        for (int u = 0; u < 8; ++u) {
            a0 += bf_lo(v[u].x); a1 += bf_hi(v[u].x);
            a2 += bf_lo(v[u].y); a3 += bf_hi(v[u].y);
            a4 += bf_lo(v[u].z); a5 += bf_hi(v[u].z);
            a6 += bf_lo(v[u].w); a7 += bf_hi(v[u].w);
        }
    }
    uint4 o;
    o.x = (unsigned int)f2bf(a0 * sinv) | ((unsigned int)f2bf(a1 * sinv) << 16);
    o.y = (unsigned int)f2bf(a2 * sinv) | ((unsigned int)f2bf(a3 * sinv) << 16);
    o.z = (unsigned int)f2bf(a4 * sinv) | ((unsigned int)f2bf(a5 * sinv) << 16);
    o.w = (unsigned int)f2bf(a6 * sinv) | ((unsigned int)f2bf(a7 * sinv) << 16);
    *(uint4*)&agg_out[(size_t)node * F + cl * 8] = o;   // dense [N][128]
}

// ---------------- layers 0/1 fused linear via MFMA: h' = relu([h|agg] @ Wt^T + b) ----------------
__global__ __launch_bounds__(256) void linear01_k(const unsigned short* __restrict__ h,
                                                  const unsigned short* __restrict__ agg,
                                                  const unsigned short* __restrict__ Wt,
                                                  const float* __restrict__ bias,
                                                  unsigned short* __restrict__ hout) {
    constexpr int CPW = 32;
    constexpr int NT = 2;
    const int lane = threadIdx.x & 63;
    const int wv = threadIdx.x >> 6;
    const int col0 = wv * CPW;
    const int lc = lane & 15;
    const int lg = lane >> 4;
    bf16x8 bfrag[NT][8];
    float bias_c[NT];
    #pragma unroll
    for (int nt = 0; nt < NT; ++nt) {
        int col = col0 + nt * 16 + lc;
        bias_c[nt] = bias[col];
        #pragma unroll
        for (int ks = 0; ks < 8; ++ks)
            bfrag[nt][ks] = *(const bf16x8*)&Wt[col * 256 + ks * 32 + lg * 8];
    }
    const int i0base = blockIdx.x * 128;
    for (int s = 0; s < 8; ++s) {
        int i0 = i0base + s * 16;
        if (i0 >= N) return;
        const unsigned short* hrow = &h[(size_t)(i0 + lc) * F];
        const unsigned short* arow = &agg[(size_t)(i0 + lc) * F];
        f32x4 acc[NT];
        #pragma unroll
        for (int nt = 0; nt < NT; ++nt) {
            acc[nt][0] = bias_c[nt]; acc[nt][1] = bias_c[nt];
            acc[nt][2] = bias_c[nt]; acc[nt][3] = bias_c[nt];
        }
        #pragma unroll
        for (int ks = 0; ks < 4; ++ks) {
            bf16x8 af = *(const bf16x8*)&hrow[ks * 32 + lg * 8];
            #pragma unroll
            for (int nt = 0; nt < NT; ++nt)
                acc[nt] = __builtin_amdgcn_mfma_f32_16x16x32_bf16(af, bfrag[nt][ks], acc[nt], 0, 0, 0);
        }
        #pragma unroll
        for (int ks = 0; ks < 4; ++ks) {
            bf16x8 af = *(const bf16x8*)&arow[ks * 32 + lg * 8];
            #pragma unroll
            for (int nt = 0; nt < NT; ++nt)
                acc[nt] = __builtin_amdgcn_mfma_f32_16x16x32_bf16(af, bfrag[nt][ks + 4], acc[nt], 0, 0, 0);
        }
        #pragma unroll
        for (int nt = 0; nt < NT; ++nt) {
            int col = col0 + nt * 16 + lc;
            #pragma unroll
            for (int r = 0; r < 4; ++r) {
                int orow = i0 + lg * 4 + r;
                hout[(size_t)orow * F + col] = f2bf(fmaxf(acc[nt][r], 0.f));
            }
        }
    }
}

// ---------------- layer2 GEMM: [P|Q] = h @ Wc^T; P=h@Ws2+b2 -> f32 out, Q=h@Wn2 -> bf16 ----------------
__global__ __launch_bounds__(256) void linear2_k(const unsigned short* __restrict__ h,
                                                 const unsigned short* __restrict__ Wc,
                                                 const float* __restrict__ bias,
                                                 float* __restrict__ out,
                                                 unsigned short* __restrict__ Q) {
    constexpr int CPW = 32;
    constexpr int NT = 2;
    const int lane = threadIdx.x & 63;
    const int wv = threadIdx.x >> 6;
    const int col0 = wv * CPW;  // wv 0/1 -> P cols 0..63, wv 2/3 -> Q cols 64..127
    const int lc = lane & 15;
    const int lg = lane >> 4;
    bf16x8 bfrag[NT][4];
    float bias_c[NT];
    #pragma unroll
    for (int nt = 0; nt < NT; ++nt) {
        int col = col0 + nt * 16 + lc;
        bias_c[nt] = (wv < 2) ? bias[col] : 0.f;
        #pragma unroll
        for (int ks = 0; ks < 4; ++ks)
            bfrag[nt][ks] = *(const bf16x8*)&Wc[col * 128 + ks * 32 + lg * 8];
    }
    const int i0base = blockIdx.x * 128;
    for (int s = 0; s < 8; ++s) {
        int i0 = i0base + s * 16;
        if (i0 >= N) return;
        const unsigned short* arow = &h[(size_t)(i0 + lc) * F];
        f32x4 acc[NT];
        #pragma unroll
        for (int nt = 0; nt < NT; ++nt) {
            acc[nt][0] = bias_c[nt]; acc[nt][1] = bias_c[nt];
            acc[nt][2] = bias_c[nt]; acc[nt][3] = bias_c[nt];
        }
        #pragma unroll
        for (int ks = 0; ks < 4; ++ks) {
            bf16x8 af = *(const bf16x8*)&arow[ks * 32 + lg * 8];
            #pragma unroll
            for (int nt = 0; nt < NT; ++nt)
                acc[nt] = __builtin_amdgcn_mfma_f32_16x16x32_bf16(af, bfrag[nt][ks], acc[nt], 0, 0, 0);
        }
        #pragma unroll
        for (int nt = 0; nt < NT; ++nt) {
            int col = col0 + nt * 16 + lc;
            #pragma unroll
            for (int r = 0; r < 4; ++r) {
                int orow = i0 + lg * 4 + r;
                float v = acc[nt][r];
                if (wv < 2) out[(size_t)orow * 64 + col] = v;
                else        Q[(size_t)orow * 64 + (col - 64)] = f2bf(v);
            }
        }
    }
}

// ---------------- 64-col mean aggregation of Q, added into f32 out ----------------
__global__ __launch_bounds__(256) void aggregate64_add_k(const unsigned short* __restrict__ Q,
                                                         const int* __restrict__ row_beg,
                                                         const int* __restrict__ degs,
                                                         const int* __restrict__ esrc,
                                                         const float* __restrict__ inv_deg,
                                                         float* __restrict__ out) {
    const int lane = threadIdx.x & 63;
    const int wv = threadIdx.x >> 6;
    const int slot = lane >> 3;        // node slot 0..7
    const int cl = lane & 7;           // 8 cols each
    const int node = blockIdx.x * 32 + wv * 8 + slot;  // grid = N/32 exactly
    const int beg = row_beg[node];
    const int cnt = degs[node];
    const float sinv = inv_deg[node];
    int wmax = cnt;
    wmax = max(wmax, __shfl_xor(wmax, 8));
    wmax = max(wmax, __shfl_xor(wmax, 16));
    wmax = max(wmax, __shfl_xor(wmax, 32));
    float a0 = 0.f, a1 = 0.f, a2 = 0.f, a3 = 0.f;
    float a4 = 0.f, a5 = 0.f, a6 = 0.f, a7 = 0.f;
    for (int j = 0; j < wmax; j += 8) {
        int idx[8];
        uint4 v[8];
        #pragma unroll
        for (int u = 0; u < 8; ++u)
            idx[u] = (j + u < cnt) ? __builtin_nontemporal_load(&esrc[beg + j + u]) : -1;
        #pragma unroll
        for (int u = 0; u < 8; ++u) {
            if (idx[u] >= 0)
                v[u] = *(const uint4*)&Q[(size_t)idx[u] * 64 + cl * 8];
            else { v[u].x = 0u; v[u].y = 0u; v[u].z = 0u; v[u].w = 0u; }
        }
        #pragma unroll
        for (int u = 0; u < 8; ++u) {
            a0 += bf_lo(v[u].x); a1 += bf_hi(v[u].x);
            a2 += bf_lo(v[u].y); a3 += bf_hi(v[u].y);
            a4 += bf_lo(v[u].z); a5 += bf_hi(v[u].z);
            a6 += bf_lo(v[u].w); a7 += bf_hi(v[u].w);
        }
    }
    float4* p0 = (float4*)&out[(size_t)node * 64 + cl * 8];
    float4 pv = *p0;
    pv.x += a0 * sinv; pv.y += a1 * sinv; pv.z += a2 * sinv; pv.w += a3 * sinv;
    *p0 = pv;
    float4* p1 = p0 + 1;
    float4 pw = *p1;
    pw.x += a4 * sinv; pw.y += a5 * sinv; pw.z += a6 * sinv; pw.w += a7 * sinv;
    *p1 = pw;
}

extern "C" void kernel_launch(void* const* d_in, const int* in_sizes, int n_in,
                              void* d_out, int out_size, void* d_ws, size_t ws_size,
                              hipStream_t stream) {
    const float* feat = (const float*)d_in[0];
    const int*   src  = (const int*)d_in[1];
    const int*   dst  = (const int*)d_in[2];
    const float* Ws0  = (const float*)d_in[3];
    const float* Wn0  = (const float*)d_in[4];
    const float* b0   = (const float*)d_in[5];
    const float* Ws1  = (const float*)d_in[6];
    const float* Wn1  = (const float*)d_in[7];
    const float* b1   = (const float*)d_in[8];
    const float* Ws2  = (const float*)d_in[9];
    const float* Wn2  = (const float*)d_in[10];
    const float* b2   = (const float*)d_in[11];
    float* out = (float*)d_out;

    char* ws = (char*)d_ws;
    size_t off = 0;
    auto alloc = [&](size_t bytes) {
        void* p = ws + off;
        off = (off + bytes + 255) & ~(size_t)255;
        return p;
    };
    unsigned short* hA  = (unsigned short*)alloc((size_t)NPAD * F * 2);
    unsigned short* hB  = (unsigned short*)alloc((size_t)NPAD * F * 2);
    unsigned short* agg = (unsigned short*)alloc((size_t)NPAD * F * 2);
    unsigned short* Qb  = (unsigned short*)alloc((size_t)N * 64 * 2);
    unsigned short* Wt0 = (unsigned short*)alloc((size_t)128 * 256 * 2);
    unsigned short* Wt1 = (unsigned short*)alloc((size_t)128 * 256 * 2);
    unsigned short* Wc2 = (unsigned short*)alloc((size_t)128 * 128 * 2);
    float* inv     = (float*)alloc((size_t)N * 4);
    int*   row_beg = (int*)alloc((size_t)N * 4);
    int*   degs    = (int*)alloc((size_t)N * 4);
    int*   bcur    = (int*)alloc((size_t)NB * 4);
    unsigned int* ebuf = (unsigned int*)alloc((size_t)NB * CAPB * 4);
    int*   esrc    = (int*)alloc((size_t)NB * CAPB * 4);
    (void)ws_size; (void)in_sizes; (void)n_in; (void)out_size;

    // ---- prep (conv + weights + bcur zero) and CSR build ----
    prep_all_k<<<12500 + 320 + 1, 256, 0, stream>>>(
        feat, hA, Ws0, Wn0, Ws1, Wn1, Ws2, Wn2, Wt0, Wt1, Wc2, bcur);
    partition_k<<<PGRID, 256, 0, stream>>>(src, dst, bcur, ebuf);
    csr_sort_k<<<NB, 256, 0, stream>>>(ebuf, bcur, row_beg, degs, inv, esrc);

    const int lin_grid = (N + 127) / 128;
    // layer 0
    aggregate128_k<<<N / 16, 256, 0, stream>>>(hA, agg, row_beg, degs, esrc, inv);
    linear01_k<<<lin_grid, 256, 0, stream>>>(hA, agg, Wt0, b0, hB);
    // layer 1
    aggregate128_k<<<N / 16, 256, 0, stream>>>(hB, agg, row_beg, degs, esrc, inv);
    linear01_k<<<lin_grid, 256, 0, stream>>>(hB, agg, Wt1, b1, hA);
    // layer 2: P = h@Ws2+b2 -> out, Q = h@Wn2; then out += mean-gather(Q)
    linear2_k<<<lin_grid, 256, 0, stream>>>(hA, Wc2, b2, out, Qb);
    aggregate64_add_k<<<N / 32, 256, 0, stream>>>(Qb, row_beg, degs, esrc, inv, out);
}